// Round 2
// baseline (190.072 us; speedup 1.0000x reference)
//
#include <hip/hip_runtime.h>

// Problem constants
#define B_  32
#define M_  64
#define K_  36
#define DS_ 512
#define DX_ 128
#define DQ_ 512
#define H_  256

#define BK  32            // K-chunk staged in LDS (32 x 256 floats = 32 KB)

// ---------------------------------------------------------------------------
// kern1 (grid 360 x 512): all GEMMs. B-panel LDS-staged + double-buffered,
// A rows via wave-uniform scalar loads, accumulators in registers.
//   blocks [0,256):   16 s2-rows, mat = bid&1 (0: pre_s = s2@w_s, 1: h1 = s2@h_w1)
//                     K=512 in 16 stages of BK=32. Waves 0-3: rows 0-7,
//                     waves 4-7: rows 8-15 (readfirstlane keeps A scalar).
//   blocks [256,328): px[bk,h] = x0[bk]@w_x + score_b1   (K=128, 4 stages)
//   blocks [328,360): qpre[b,h] = q[b]@w_q               (K=512 split 2x256)
// ---------------------------------------------------------------------------
__global__ __launch_bounds__(512) void kern1(
    const float* __restrict__ s2,        // (2048,512)
    const float* __restrict__ x0,        // (1152,128)
    const float* __restrict__ q,         // (32,512)
    const float* __restrict__ score_w1,  // (1152,256)
    const float* __restrict__ score_b1,  // (256)
    const float* __restrict__ h_w1,      // (512,256)
    float* __restrict__ pre_s,           // (2048,256)
    float* __restrict__ h1,              // (2048,256)
    float* __restrict__ px,              // (1152,256)
    float* __restrict__ qpre)            // (32,256)
{
    __shared__ float Bs[2][BK * H_];     // 64 KB double-buffered B panel
    const int t   = threadIdx.x;
    const int bid = blockIdx.x;
    const int h   = t & 255;
    // wave-uniform row-half base (waves 0-3 -> 0, waves 4-7 -> 8)
    const int rbase = __builtin_amdgcn_readfirstlane((t >> 8) * 8);

    if (bid < 256) {                     // ---- s2 GEMMs ----
        const int tile = bid >> 1, mat = bid & 1;
        const float* W = mat ? h_w1 : score_w1;           // (512,256)
        const float* A = s2 + ((size_t)tile * 16 + rbase) * DS_;  // uniform

        float acc[8];
        #pragma unroll
        for (int r = 0; r < 8; ++r) acc[r] = 0.f;

        float4 stg[4];
        #pragma unroll
        for (int i = 0; i < 4; ++i)
            stg[i] = *(const float4*)(W + t * 4 + i * 2048);
        #pragma unroll
        for (int i = 0; i < 4; ++i)
            *(float4*)&Bs[0][t * 4 + i * 2048] = stg[i];
        __syncthreads();

        for (int s = 0; s < 16; ++s) {
            const int cur = s & 1;
            if (s < 15) {                // issue next-stage loads early (T14)
                const float* src = W + (size_t)(s + 1) * (BK * H_);
                #pragma unroll
                for (int i = 0; i < 4; ++i)
                    stg[i] = *(const float4*)(src + t * 4 + i * 2048);
            }
            const float* a0 = A + s * BK;
            const float* bb = &Bs[cur][h];
            #pragma unroll
            for (int kq = 0; kq < 8; ++kq) {
                const float b0 = bb[(size_t)(kq * 4 + 0) * H_];
                const float b1 = bb[(size_t)(kq * 4 + 1) * H_];
                const float b2 = bb[(size_t)(kq * 4 + 2) * H_];
                const float b3 = bb[(size_t)(kq * 4 + 3) * H_];
                #pragma unroll
                for (int r = 0; r < 8; ++r) {
                    const float4 a = *(const float4*)(a0 + (size_t)r * DS_ + kq * 4);
                    acc[r] = fmaf(a.x, b0, acc[r]);
                    acc[r] = fmaf(a.y, b1, acc[r]);
                    acc[r] = fmaf(a.z, b2, acc[r]);
                    acc[r] = fmaf(a.w, b3, acc[r]);
                }
            }
            if (s < 15) {                // write next buffer late
                #pragma unroll
                for (int i = 0; i < 4; ++i)
                    *(float4*)&Bs[cur ^ 1][t * 4 + i * 2048] = stg[i];
            }
            __syncthreads();
        }
        float* dst = (mat ? h1 : pre_s) + ((size_t)tile * 16 + rbase) * H_ + h;
        #pragma unroll
        for (int r = 0; r < 8; ++r)
            dst[(size_t)r * H_] = acc[r];

    } else if (bid < 328) {              // ---- px blocks ----
        const int tile = bid - 256;
        const float* W = score_w1 + (size_t)DS_ * H_;     // w_x (128,256)
        const float* A = x0 + ((size_t)tile * 16 + rbase) * DX_;  // uniform

        float acc[8];
        #pragma unroll
        for (int r = 0; r < 8; ++r) acc[r] = 0.f;

        float4 stg[4];
        #pragma unroll
        for (int i = 0; i < 4; ++i)
            stg[i] = *(const float4*)(W + t * 4 + i * 2048);
        #pragma unroll
        for (int i = 0; i < 4; ++i)
            *(float4*)&Bs[0][t * 4 + i * 2048] = stg[i];
        __syncthreads();

        for (int s = 0; s < 4; ++s) {
            const int cur = s & 1;
            if (s < 3) {
                const float* src = W + (size_t)(s + 1) * (BK * H_);
                #pragma unroll
                for (int i = 0; i < 4; ++i)
                    stg[i] = *(const float4*)(src + t * 4 + i * 2048);
            }
            const float* a0 = A + s * BK;
            const float* bb = &Bs[cur][h];
            #pragma unroll
            for (int kq = 0; kq < 8; ++kq) {
                const float b0 = bb[(size_t)(kq * 4 + 0) * H_];
                const float b1 = bb[(size_t)(kq * 4 + 1) * H_];
                const float b2 = bb[(size_t)(kq * 4 + 2) * H_];
                const float b3 = bb[(size_t)(kq * 4 + 3) * H_];
                #pragma unroll
                for (int r = 0; r < 8; ++r) {
                    const float4 a = *(const float4*)(a0 + (size_t)r * DX_ + kq * 4);
                    acc[r] = fmaf(a.x, b0, acc[r]);
                    acc[r] = fmaf(a.y, b1, acc[r]);
                    acc[r] = fmaf(a.z, b2, acc[r]);
                    acc[r] = fmaf(a.w, b3, acc[r]);
                }
            }
            if (s < 3) {
                #pragma unroll
                for (int i = 0; i < 4; ++i)
                    *(float4*)&Bs[cur ^ 1][t * 4 + i * 2048] = stg[i];
            }
            __syncthreads();
        }
        const float b1v = score_b1[h];
        float* dst = px + ((size_t)tile * 16 + rbase) * H_ + h;
        #pragma unroll
        for (int r = 0; r < 8; ++r)
            dst[(size_t)r * H_] = acc[r] + b1v;

    } else {                             // ---- qpre blocks ----
        const int b  = bid - 328;
        const int kh = t >> 8;
        float* comb = &Bs[0][0];
        const float* qp = q + (size_t)b * DQ_ + kh * 256;            // uniform
        const float* wq = score_w1 + (size_t)(DS_ + DX_ + kh * 256) * H_ + h;
        float a0 = 0.f, a1 = 0.f, a2 = 0.f, a3 = 0.f;
        for (int d = 0; d < 256; d += 4) {
            const float4 q4 = *(const float4*)(qp + d);
            a0 = fmaf(q4.x, wq[(size_t)(d + 0) * H_], a0);
            a1 = fmaf(q4.y, wq[(size_t)(d + 1) * H_], a1);
            a2 = fmaf(q4.z, wq[(size_t)(d + 2) * H_], a2);
            a3 = fmaf(q4.w, wq[(size_t)(d + 3) * H_], a3);
        }
        const float s = (a0 + a1) + (a2 + a3);
        if (kh) comb[h] = s;
        __syncthreads();
        if (!kh) qpre[(size_t)b * H_ + h] = s + comb[h];
    }
}

// ---------------------------------------------------------------------------
// kern2 (grid 512 x 256): hs = relu(h1 + h_b1) @ h_w2  (no h_b2 -- added in
// kern3 since sum(att)=1). 4 rows/block, split-K=2, float4 w2 loads.
// ---------------------------------------------------------------------------
__global__ __launch_bounds__(256) void kern2(
    const float* __restrict__ h1,        // (2048,256)
    const float* __restrict__ h_b1,      // (256)
    const float* __restrict__ h_w2,      // (256,128)
    float* __restrict__ hs)              // (2048,128)
{
    __shared__ float A[4 * H_];          // relu'd rows
    __shared__ float part[4][DX_];
    const int t  = threadIdx.x;
    const int r0 = blockIdx.x * 4;

    {
        const int flat = t * 4;
        const float4 v  = *(const float4*)(h1 + (size_t)r0 * H_ + flat);
        const float4 bb = *(const float4*)(h_b1 + (flat & (H_ - 1)));
        float4 a;
        a.x = fmaxf(v.x + bb.x, 0.f);
        a.y = fmaxf(v.y + bb.y, 0.f);
        a.z = fmaxf(v.z + bb.z, 0.f);
        a.w = fmaxf(v.w + bb.w, 0.f);
        *(float4*)&A[flat] = a;
    }
    __syncthreads();

    const int fq  = (t & 31) * 4;
    const int g   = t >> 5;
    const int row = g & 3, kh = g >> 2;
    const float* ap = &A[row * H_ + kh * 128];
    const float* wp = h_w2 + (size_t)(kh * 128) * DX_ + fq;

    float4 acc = {0.f, 0.f, 0.f, 0.f};
    #pragma unroll 4
    for (int d = 0; d < 128; d += 4) {
        const float a0 = ap[d], a1 = ap[d + 1], a2 = ap[d + 2], a3 = ap[d + 3];
        const float4 w0  = *(const float4*)(wp + (size_t)(d + 0) * DX_);
        const float4 w1  = *(const float4*)(wp + (size_t)(d + 1) * DX_);
        const float4 w2v = *(const float4*)(wp + (size_t)(d + 2) * DX_);
        const float4 w3  = *(const float4*)(wp + (size_t)(d + 3) * DX_);
        acc.x = fmaf(a0, w0.x, acc.x); acc.y = fmaf(a0, w0.y, acc.y);
        acc.z = fmaf(a0, w0.z, acc.z); acc.w = fmaf(a0, w0.w, acc.w);
        acc.x = fmaf(a1, w1.x, acc.x); acc.y = fmaf(a1, w1.y, acc.y);
        acc.z = fmaf(a1, w1.z, acc.z); acc.w = fmaf(a1, w1.w, acc.w);
        acc.x = fmaf(a2, w2v.x, acc.x); acc.y = fmaf(a2, w2v.y, acc.y);
        acc.z = fmaf(a2, w2v.z, acc.z); acc.w = fmaf(a2, w2v.w, acc.w);
        acc.x = fmaf(a3, w3.x, acc.x); acc.y = fmaf(a3, w3.y, acc.y);
        acc.z = fmaf(a3, w3.z, acc.z); acc.w = fmaf(a3, w3.w, acc.w);
    }
    if (kh) *(float4*)&part[row][fq] = acc;
    __syncthreads();
    if (!kh) {
        const float4 p = *(const float4*)&part[row][fq];
        float4 o;
        o.x = acc.x + p.x; o.y = acc.y + p.y;
        o.z = acc.z + p.z; o.w = acc.w + p.w;
        *(float4*)(hs + (size_t)(r0 + row) * DX_ + fq) = o;
    }
}

// ---------------------------------------------------------------------------
// kern3 (grid 288 = 32 b x 9 kgroups, 256 threads): logits+softmax+agg.
//   (unchanged from previous round -- verified correct)
// ---------------------------------------------------------------------------
__global__ __launch_bounds__(256) void kern3(
    const float* __restrict__ pre_s,     // (2048,256)
    const float* __restrict__ px,        // (1152,256)
    const float* __restrict__ qpre,      // (32,256)
    const float* __restrict__ score_w2,  // (256,1)
    const float* __restrict__ hs,        // (2048,128)
    const float* __restrict__ h_b2,      // (128)
    const float* __restrict__ x0,        // (1152,128)
    float* __restrict__ out)             // (1152,256)
{
    __shared__ float psf[M_ * H_];       // 64 KB, swizzled
    __shared__ float cw4[4][H_];
    __shared__ float att4[M_ * 4];
    __shared__ float pr[4][DX_];

    const int t   = threadIdx.x;
    const int b   = blockIdx.x / 9;
    const int k0  = (blockIdx.x % 9) * 4;
    const int bk0 = b * K_ + k0;

    const float* psrc = pre_s + (size_t)b * M_ * H_;
    #pragma unroll
    for (int i = 0; i < 16; ++i) {
        const int flat = t * 4 + i * 1024;
        const float4 v = *(const float4*)(psrc + flat);
        const int m = flat >> 8, hh = flat & 255;
        *(float4*)&psf[m * H_ + (hh ^ ((m & 7) << 2))] = v;
    }
    {
        const float qv = qpre[(size_t)b * H_ + t];
        #pragma unroll
        for (int kk = 0; kk < 4; ++kk)
            cw4[kk][t] = px[(size_t)(bk0 + kk) * H_ + t] + qv;
    }
    __syncthreads();

    {
        const int kk = t >> 6, m = t & 63;
        const int sw = (m & 7) << 2;
        const float* prow = &psf[m * H_];
        const float* crow = &cw4[kk][0];
        float lg = 0.f;
        for (int d = 0; d < 256; d += 4) {
            const float4 p = *(const float4*)&prow[d ^ sw];
            const float4 c = *(const float4*)&crow[d];
            const float4 v = *(const float4*)(score_w2 + d);
            lg += fmaxf(p.x + c.x, 0.f) * v.x + fmaxf(p.y + c.y, 0.f) * v.y
                + fmaxf(p.z + c.z, 0.f) * v.z + fmaxf(p.w + c.w, 0.f) * v.w;
        }
        float mx = lg;
        #pragma unroll
        for (int off = 32; off > 0; off >>= 1)
            mx = fmaxf(mx, __shfl_xor(mx, off, 64));
        const float e = expf(lg - mx);
        float sm = e;
        #pragma unroll
        for (int off = 32; off > 0; off >>= 1)
            sm += __shfl_xor(sm, off, 64);
        att4[m * 4 + kk] = e / sm;
    }
    __syncthreads();

    const int f = t & 127, half = t >> 7;
    {
        const float* hsp = hs + ((size_t)b * M_ + half * 32) * DX_ + f;
        float r0 = 0.f, r1 = 0.f, r2 = 0.f, r3 = 0.f;
        for (int m = 0; m < 32; ++m) {
            const float hv = hsp[(size_t)m * DX_];
            const float4 a = *(const float4*)&att4[(half * 32 + m) * 4];
            r0 = fmaf(a.x, hv, r0);
            r1 = fmaf(a.y, hv, r1);
            r2 = fmaf(a.z, hv, r2);
            r3 = fmaf(a.w, hv, r3);
        }
        if (half) {
            pr[0][f] = r0; pr[1][f] = r1; pr[2][f] = r2; pr[3][f] = r3;
        }
        __syncthreads();
        if (!half) {
            const float b2 = h_b2[f];
            out[(size_t)(bk0 + 0) * (2 * DX_) + DX_ + f] = r0 + pr[0][f] + b2;
            out[(size_t)(bk0 + 1) * (2 * DX_) + DX_ + f] = r1 + pr[1][f] + b2;
            out[(size_t)(bk0 + 2) * (2 * DX_) + DX_ + f] = r2 + pr[2][f] + b2;
            out[(size_t)(bk0 + 3) * (2 * DX_) + DX_ + f] = r3 + pr[3][f] + b2;
        }
    }
    #pragma unroll
    for (int j = 0; j < 2; ++j) {
        const int kk = half * 2 + j;
        out[(size_t)(bk0 + kk) * (2 * DX_) + f] = x0[(size_t)(bk0 + kk) * DX_ + f];
    }
}

extern "C" void kernel_launch(void* const* d_in, const int* in_sizes, int n_in,
                              void* d_out, int out_size, void* d_ws, size_t ws_size,
                              hipStream_t stream) {
    (void)in_sizes; (void)n_in; (void)out_size; (void)ws_size;
    const float* s2       = (const float*)d_in[0];
    const float* x0       = (const float*)d_in[1];
    const float* q        = (const float*)d_in[2];
    const float* score_w1 = (const float*)d_in[3];
    const float* score_b1 = (const float*)d_in[4];
    const float* score_w2 = (const float*)d_in[5];
    // d_in[6] = score_b2 (cancels in softmax)
    const float* h_w1     = (const float*)d_in[7];
    const float* h_b1     = (const float*)d_in[8];
    const float* h_w2     = (const float*)d_in[9];
    const float* h_b2     = (const float*)d_in[10];
    float* out = (float*)d_out;

    float* ws    = (float*)d_ws;
    float* pre_s = ws;                                   // 2048*256
    float* h1    = pre_s + (size_t)B_ * M_ * H_;         // 2048*256
    float* px    = h1    + (size_t)B_ * M_ * H_;         // 1152*256
    float* qpre  = px    + (size_t)B_ * K_ * H_;         // 32*256
    float* hs    = qpre  + (size_t)B_ * H_;              // 2048*128

    kern1<<<360, 512, 0, stream>>>(s2, x0, q, score_w1, score_b1, h_w1,
                                   pre_s, h1, px, qpre);
    kern2<<<512, 256, 0, stream>>>(h1, h_b1, h_w2, hs);
    kern3<<<288, 256, 0, stream>>>(pre_s, px, qpre, score_w2, hs, h_b2, x0, out);
}

// Round 3
// 133.331 us; speedup vs baseline: 1.4256x; 1.4256x over previous
//
#include <hip/hip_runtime.h>

// Problem constants
#define B_  32
#define M_  64
#define K_  36
#define DS_ 512
#define DX_ 128
#define DQ_ 512
#define H_  256

#define ROWS 8   // rows per GEMM block in kern1

// ---------------------------------------------------------------------------
// kern1 (grid 688 x 256): all GEMMs + fused hs. No barriers in hot loops,
// no split-K, no atomics. B via per-lane coalesced global loads (L2-hot),
// A via block-uniform scalar loads, 8 accumulators per thread.
//   blocks [0,512):   tile = bid>>1 (8 s2-rows), mat = bid&1.
//     mat=0: pre_s[rows,h] = s2@w_s ; mat=1: h1 rows kept in regs, then
//            hs[rows,f] = relu(h1+h_b1) @ h_w2 via 8KB LDS (fused kern2).
//   blocks [512,656): px[8 rows,h] = x0@w_x + score_b1   (K=128)
//   blocks [656,688): qpre[b,h] = q[b]@w_q               (K=512)
// ---------------------------------------------------------------------------
__global__ __launch_bounds__(256) void kern1(
    const float* __restrict__ s2,        // (2048,512)
    const float* __restrict__ x0,        // (1152,128)
    const float* __restrict__ q,         // (32,512)
    const float* __restrict__ score_w1,  // (1152,256)
    const float* __restrict__ score_b1,  // (256)
    const float* __restrict__ h_w1,      // (512,256)
    const float* __restrict__ h_b1,      // (256)
    const float* __restrict__ h_w2,      // (256,128)
    float* __restrict__ pre_s,           // (2048,256)
    float* __restrict__ px,              // (1152,256)
    float* __restrict__ qpre,            // (32,256)
    float* __restrict__ hs)              // (2048,128)
{
    __shared__ float Ar[ROWS][H_];       // 8 KB, used only by mat=1 blocks
    const int t   = threadIdx.x;
    const int bid = blockIdx.x;

    if (bid < 512) {                     // ---- s2 GEMMs ----
        const int tile = bid >> 1, mat = bid & 1;
        const float* W  = mat ? h_w1 : score_w1;              // (512,256)
        const float* A  = s2 + (size_t)tile * ROWS * DS_;     // block-uniform
        const float* Wp = W + t;

        float acc[ROWS];
        #pragma unroll
        for (int r = 0; r < ROWS; ++r) acc[r] = 0.f;

        #pragma unroll 2
        for (int k = 0; k < DS_; k += 4) {
            const float b0 = Wp[(size_t)(k + 0) * H_];
            const float b1 = Wp[(size_t)(k + 1) * H_];
            const float b2 = Wp[(size_t)(k + 2) * H_];
            const float b3 = Wp[(size_t)(k + 3) * H_];
            #pragma unroll
            for (int r = 0; r < ROWS; ++r) {
                const float4 a = *(const float4*)(A + (size_t)r * DS_ + k);
                acc[r] = fmaf(a.x, b0, acc[r]);
                acc[r] = fmaf(a.y, b1, acc[r]);
                acc[r] = fmaf(a.z, b2, acc[r]);
                acc[r] = fmaf(a.w, b3, acc[r]);
            }
        }

        if (!mat) {                      // pre_s: plain store
            float* dst = pre_s + (size_t)tile * ROWS * H_ + t;
            #pragma unroll
            for (int r = 0; r < ROWS; ++r)
                dst[(size_t)r * H_] = acc[r];
        } else {                         // fused: hs = relu(h1+b1) @ h_w2
            const float b1v = h_b1[t];
            #pragma unroll
            for (int r = 0; r < ROWS; ++r)
                Ar[r][t] = fmaxf(acc[r] + b1v, 0.f);
            __syncthreads();

            const int f  = t & 127;
            const int rh = t >> 7;       // rows rh*4 .. rh*4+3
            const float* w2p = h_w2 + f;
            float o0 = 0.f, o1 = 0.f, o2 = 0.f, o3 = 0.f;
            #pragma unroll 2
            for (int k = 0; k < H_; k += 4) {
                const float w0 = w2p[(size_t)(k + 0) * DX_];
                const float w1 = w2p[(size_t)(k + 1) * DX_];
                const float w2v = w2p[(size_t)(k + 2) * DX_];
                const float w3 = w2p[(size_t)(k + 3) * DX_];
                const float4 a0 = *(const float4*)&Ar[rh * 4 + 0][k];
                const float4 a1 = *(const float4*)&Ar[rh * 4 + 1][k];
                const float4 a2 = *(const float4*)&Ar[rh * 4 + 2][k];
                const float4 a3 = *(const float4*)&Ar[rh * 4 + 3][k];
                o0 = fmaf(a0.x, w0, o0); o0 = fmaf(a0.y, w1, o0);
                o0 = fmaf(a0.z, w2v, o0); o0 = fmaf(a0.w, w3, o0);
                o1 = fmaf(a1.x, w0, o1); o1 = fmaf(a1.y, w1, o1);
                o1 = fmaf(a1.z, w2v, o1); o1 = fmaf(a1.w, w3, o1);
                o2 = fmaf(a2.x, w0, o2); o2 = fmaf(a2.y, w1, o2);
                o2 = fmaf(a2.z, w2v, o2); o2 = fmaf(a2.w, w3, o2);
                o3 = fmaf(a3.x, w0, o3); o3 = fmaf(a3.y, w1, o3);
                o3 = fmaf(a3.z, w2v, o3); o3 = fmaf(a3.w, w3, o3);
            }
            float* dst = hs + ((size_t)tile * ROWS + rh * 4) * DX_ + f;
            dst[0 * DX_] = o0;
            dst[1 * DX_] = o1;
            dst[2 * DX_] = o2;
            dst[3 * DX_] = o3;
        }

    } else if (bid < 656) {              // ---- px blocks (K=128) ----
        const int tile = bid - 512;
        const float* A  = x0 + (size_t)tile * ROWS * DX_;     // block-uniform
        const float* Wp = score_w1 + (size_t)DS_ * H_ + t;    // w_x

        float acc[ROWS];
        #pragma unroll
        for (int r = 0; r < ROWS; ++r) acc[r] = 0.f;

        #pragma unroll 2
        for (int k = 0; k < DX_; k += 4) {
            const float b0 = Wp[(size_t)(k + 0) * H_];
            const float b1 = Wp[(size_t)(k + 1) * H_];
            const float b2 = Wp[(size_t)(k + 2) * H_];
            const float b3 = Wp[(size_t)(k + 3) * H_];
            #pragma unroll
            for (int r = 0; r < ROWS; ++r) {
                const float4 a = *(const float4*)(A + (size_t)r * DX_ + k);
                acc[r] = fmaf(a.x, b0, acc[r]);
                acc[r] = fmaf(a.y, b1, acc[r]);
                acc[r] = fmaf(a.z, b2, acc[r]);
                acc[r] = fmaf(a.w, b3, acc[r]);
            }
        }
        const float b1v = score_b1[t];
        float* dst = px + (size_t)tile * ROWS * H_ + t;
        #pragma unroll
        for (int r = 0; r < ROWS; ++r)
            dst[(size_t)r * H_] = acc[r] + b1v;

    } else {                             // ---- qpre blocks ----
        const int b = bid - 656;
        const float* qp = q + (size_t)b * DQ_;                // block-uniform
        const float* wq = score_w1 + (size_t)(DS_ + DX_) * H_ + t;
        float a0 = 0.f, a1 = 0.f, a2 = 0.f, a3 = 0.f;
        #pragma unroll 2
        for (int d = 0; d < DQ_; d += 4) {
            const float4 q4 = *(const float4*)(qp + d);
            a0 = fmaf(q4.x, wq[(size_t)(d + 0) * H_], a0);
            a1 = fmaf(q4.y, wq[(size_t)(d + 1) * H_], a1);
            a2 = fmaf(q4.z, wq[(size_t)(d + 2) * H_], a2);
            a3 = fmaf(q4.w, wq[(size_t)(d + 3) * H_], a3);
        }
        qpre[(size_t)b * H_ + t] = (a0 + a1) + (a2 + a3);
    }
}

// ---------------------------------------------------------------------------
// kern3 (grid 288 = 32 b x 9 kgroups, 256 threads): logits+softmax+agg.
//   (unchanged -- verified correct in rounds 1 and 2)
// ---------------------------------------------------------------------------
__global__ __launch_bounds__(256) void kern3(
    const float* __restrict__ pre_s,     // (2048,256)
    const float* __restrict__ px,        // (1152,256)
    const float* __restrict__ qpre,      // (32,256)
    const float* __restrict__ score_w2,  // (256,1)
    const float* __restrict__ hs,        // (2048,128)
    const float* __restrict__ h_b2,      // (128)
    const float* __restrict__ x0,        // (1152,128)
    float* __restrict__ out)             // (1152,256)
{
    __shared__ float psf[M_ * H_];       // 64 KB, swizzled
    __shared__ float cw4[4][H_];
    __shared__ float att4[M_ * 4];
    __shared__ float pr[4][DX_];

    const int t   = threadIdx.x;
    const int b   = blockIdx.x / 9;
    const int k0  = (blockIdx.x % 9) * 4;
    const int bk0 = b * K_ + k0;

    const float* psrc = pre_s + (size_t)b * M_ * H_;
    #pragma unroll
    for (int i = 0; i < 16; ++i) {
        const int flat = t * 4 + i * 1024;
        const float4 v = *(const float4*)(psrc + flat);
        const int m = flat >> 8, hh = flat & 255;
        *(float4*)&psf[m * H_ + (hh ^ ((m & 7) << 2))] = v;
    }
    {
        const float qv = qpre[(size_t)b * H_ + t];
        #pragma unroll
        for (int kk = 0; kk < 4; ++kk)
            cw4[kk][t] = px[(size_t)(bk0 + kk) * H_ + t] + qv;
    }
    __syncthreads();

    {
        const int kk = t >> 6, m = t & 63;
        const int sw = (m & 7) << 2;
        const float* prow = &psf[m * H_];
        const float* crow = &cw4[kk][0];
        float lg = 0.f;
        for (int d = 0; d < 256; d += 4) {
            const float4 p = *(const float4*)&prow[d ^ sw];
            const float4 c = *(const float4*)&crow[d];
            const float4 v = *(const float4*)(score_w2 + d);
            lg += fmaxf(p.x + c.x, 0.f) * v.x + fmaxf(p.y + c.y, 0.f) * v.y
                + fmaxf(p.z + c.z, 0.f) * v.z + fmaxf(p.w + c.w, 0.f) * v.w;
        }
        float mx = lg;
        #pragma unroll
        for (int off = 32; off > 0; off >>= 1)
            mx = fmaxf(mx, __shfl_xor(mx, off, 64));
        const float e = expf(lg - mx);
        float sm = e;
        #pragma unroll
        for (int off = 32; off > 0; off >>= 1)
            sm += __shfl_xor(sm, off, 64);
        att4[m * 4 + kk] = e / sm;
    }
    __syncthreads();

    const int f = t & 127, half = t >> 7;
    {
        const float* hsp = hs + ((size_t)b * M_ + half * 32) * DX_ + f;
        float r0 = 0.f, r1 = 0.f, r2 = 0.f, r3 = 0.f;
        for (int m = 0; m < 32; ++m) {
            const float hv = hsp[(size_t)m * DX_];
            const float4 a = *(const float4*)&att4[(half * 32 + m) * 4];
            r0 = fmaf(a.x, hv, r0);
            r1 = fmaf(a.y, hv, r1);
            r2 = fmaf(a.z, hv, r2);
            r3 = fmaf(a.w, hv, r3);
        }
        if (half) {
            pr[0][f] = r0; pr[1][f] = r1; pr[2][f] = r2; pr[3][f] = r3;
        }
        __syncthreads();
        if (!half) {
            const float b2 = h_b2[f];
            out[(size_t)(bk0 + 0) * (2 * DX_) + DX_ + f] = r0 + pr[0][f] + b2;
            out[(size_t)(bk0 + 1) * (2 * DX_) + DX_ + f] = r1 + pr[1][f] + b2;
            out[(size_t)(bk0 + 2) * (2 * DX_) + DX_ + f] = r2 + pr[2][f] + b2;
            out[(size_t)(bk0 + 3) * (2 * DX_) + DX_ + f] = r3 + pr[3][f] + b2;
        }
    }
    #pragma unroll
    for (int j = 0; j < 2; ++j) {
        const int kk = half * 2 + j;
        out[(size_t)(bk0 + kk) * (2 * DX_) + f] = x0[(size_t)(bk0 + kk) * DX_ + f];
    }
}

extern "C" void kernel_launch(void* const* d_in, const int* in_sizes, int n_in,
                              void* d_out, int out_size, void* d_ws, size_t ws_size,
                              hipStream_t stream) {
    (void)in_sizes; (void)n_in; (void)out_size; (void)ws_size;
    const float* s2       = (const float*)d_in[0];
    const float* x0       = (const float*)d_in[1];
    const float* q        = (const float*)d_in[2];
    const float* score_w1 = (const float*)d_in[3];
    const float* score_b1 = (const float*)d_in[4];
    const float* score_w2 = (const float*)d_in[5];
    // d_in[6] = score_b2 (cancels in softmax)
    const float* h_w1     = (const float*)d_in[7];
    const float* h_b1     = (const float*)d_in[8];
    const float* h_w2     = (const float*)d_in[9];
    const float* h_b2     = (const float*)d_in[10];
    float* out = (float*)d_out;

    float* ws    = (float*)d_ws;
    float* pre_s = ws;                                   // 2048*256
    float* px    = pre_s + (size_t)B_ * M_ * H_;         // 1152*256
    float* qpre  = px    + (size_t)B_ * K_ * H_;         // 32*256
    float* hs    = qpre  + (size_t)B_ * H_;              // 2048*128

    kern1<<<688, 256, 0, stream>>>(s2, x0, q, score_w1, score_b1, h_w1,
                                   h_b1, h_w2, pre_s, px, qpre, hs);
    kern3<<<288, 256, 0, stream>>>(pre_s, px, qpre, score_w2, hs, h_b2, x0, out);
}

// Round 4
// 128.495 us; speedup vs baseline: 1.4792x; 1.0376x over previous
//
#include <hip/hip_runtime.h>

// Problem constants
#define B_  32
#define M_  64
#define K_  36
#define DS_ 512
#define DX_ 128
#define DQ_ 512
#define H_  256

// kern1 grid layout
#define S2B 1024            // 512 tiles (4 rows) x 2 mats, in-block split-K=2
#define PXB 288             // 1152/4 rows
#define QPB 32

// ---------------------------------------------------------------------------
// kern1 (grid 1344 x 512 threads): all GEMMs, in-block split-K=2.
// Waves 0-3 (kh=0) and 4-7 (kh=1) each take half of K; one LDS combine +
// single barrier. ROWS=4 for max block count (TLP is the round-3 bottleneck:
// 2.7 waves/SIMD, VALUBusy 15%).
//   blocks [0,1024):     tile=bid>>1, mat=bid&1.
//       mat=0: pre_s[4 rows] = s2@w_s
//       mat=1: h1r[4 rows]   = relu(s2@h_w1 + h_b1)
//   blocks [1024,1312):  px[4 rows] = x0@w_x + score_b1   (K=128, halves of 64)
//   blocks [1312,1344):  qpre[b]    = q[b]@w_q            (K=512, halves of 256)
// B via per-lane coalesced global loads (vmcnt), A via block-uniform s_load
// (lgkmcnt) -- separate counters, no LDS in the hot loop, no barriers inside.
// ---------------------------------------------------------------------------
__global__ __launch_bounds__(512, 6) void kern1(
    const float* __restrict__ s2,        // (2048,512)
    const float* __restrict__ x0,        // (1152,128)
    const float* __restrict__ q,         // (32,512)
    const float* __restrict__ score_w1,  // (1152,256)
    const float* __restrict__ score_b1,  // (256)
    const float* __restrict__ h_w1,      // (512,256)
    const float* __restrict__ h_b1,      // (256)
    float* __restrict__ pre_s,           // (2048,256)
    float* __restrict__ h1r,             // (2048,256) relu(h1+b1)
    float* __restrict__ px,              // (1152,256)
    float* __restrict__ qpre)            // (32,256)
{
    __shared__ float comb[4 * H_];       // 4 KB split-K combine buffer
    const int t   = threadIdx.x;
    const int bid = blockIdx.x;
    const int h   = t & 255;
    const int kh  = __builtin_amdgcn_readfirstlane(t >> 8);   // wave-uniform

    if (bid < S2B) {                     // ---- s2 GEMMs ----
        const int tile = bid >> 1, mat = bid & 1;
        const float* W  = mat ? h_w1 : score_w1;              // (512,256)
        const float* A  = s2 + (size_t)tile * 4 * DS_ + kh * 256;  // uniform
        const float* Wp = W + (size_t)(kh * 256) * H_ + h;

        float acc[4];
        #pragma unroll
        for (int r = 0; r < 4; ++r) acc[r] = 0.f;

        #pragma unroll 2
        for (int k = 0; k < 256; k += 4) {
            const float b0 = Wp[(size_t)(k + 0) * H_];
            const float b1 = Wp[(size_t)(k + 1) * H_];
            const float b2 = Wp[(size_t)(k + 2) * H_];
            const float b3 = Wp[(size_t)(k + 3) * H_];
            #pragma unroll
            for (int r = 0; r < 4; ++r) {
                const float4 a = *(const float4*)(A + (size_t)r * DS_ + k);
                acc[r] = fmaf(a.x, b0, acc[r]);
                acc[r] = fmaf(a.y, b1, acc[r]);
                acc[r] = fmaf(a.z, b2, acc[r]);
                acc[r] = fmaf(a.w, b3, acc[r]);
            }
        }
        if (kh) {
            #pragma unroll
            for (int r = 0; r < 4; ++r) comb[r * H_ + h] = acc[r];
        }
        __syncthreads();
        if (!kh) {
            if (!mat) {
                float* dst = pre_s + (size_t)tile * 4 * H_ + h;
                #pragma unroll
                for (int r = 0; r < 4; ++r)
                    dst[(size_t)r * H_] = acc[r] + comb[r * H_ + h];
            } else {
                const float b1v = h_b1[h];
                float* dst = h1r + (size_t)tile * 4 * H_ + h;
                #pragma unroll
                for (int r = 0; r < 4; ++r)
                    dst[(size_t)r * H_] =
                        fmaxf(acc[r] + comb[r * H_ + h] + b1v, 0.f);
            }
        }

    } else if (bid < S2B + PXB) {        // ---- px blocks (K=128) ----
        const int tile = bid - S2B;
        const float* A  = x0 + (size_t)tile * 4 * DX_ + kh * 64;   // uniform
        const float* Wp = score_w1 + (size_t)(DS_ + kh * 64) * H_ + h;

        float acc[4];
        #pragma unroll
        for (int r = 0; r < 4; ++r) acc[r] = 0.f;

        #pragma unroll 2
        for (int k = 0; k < 64; k += 4) {
            const float b0 = Wp[(size_t)(k + 0) * H_];
            const float b1 = Wp[(size_t)(k + 1) * H_];
            const float b2 = Wp[(size_t)(k + 2) * H_];
            const float b3 = Wp[(size_t)(k + 3) * H_];
            #pragma unroll
            for (int r = 0; r < 4; ++r) {
                const float4 a = *(const float4*)(A + (size_t)r * DX_ + k);
                acc[r] = fmaf(a.x, b0, acc[r]);
                acc[r] = fmaf(a.y, b1, acc[r]);
                acc[r] = fmaf(a.z, b2, acc[r]);
                acc[r] = fmaf(a.w, b3, acc[r]);
            }
        }
        if (kh) {
            #pragma unroll
            for (int r = 0; r < 4; ++r) comb[r * H_ + h] = acc[r];
        }
        __syncthreads();
        if (!kh) {
            const float b1v = score_b1[h];
            float* dst = px + (size_t)tile * 4 * H_ + h;
            #pragma unroll
            for (int r = 0; r < 4; ++r)
                dst[(size_t)r * H_] = acc[r] + comb[r * H_ + h] + b1v;
        }

    } else {                             // ---- qpre blocks ----
        const int b = bid - (S2B + PXB);
        const float* qp = q + (size_t)b * DQ_ + kh * 256;          // uniform
        const float* wq = score_w1 + (size_t)(DS_ + DX_ + kh * 256) * H_ + h;
        float a0 = 0.f, a1 = 0.f, a2 = 0.f, a3 = 0.f;
        #pragma unroll 2
        for (int d = 0; d < 256; d += 4) {
            const float4 q4 = *(const float4*)(qp + d);
            a0 = fmaf(q4.x, wq[(size_t)(d + 0) * H_], a0);
            a1 = fmaf(q4.y, wq[(size_t)(d + 1) * H_], a1);
            a2 = fmaf(q4.z, wq[(size_t)(d + 2) * H_], a2);
            a3 = fmaf(q4.w, wq[(size_t)(d + 3) * H_], a3);
        }
        const float s = (a0 + a1) + (a2 + a3);
        if (kh) comb[h] = s;
        __syncthreads();
        if (!kh) qpre[(size_t)b * H_ + h] = s + comb[h];
    }
}

// ---------------------------------------------------------------------------
// kern2 (grid 256 x 256): hs = h1r @ h_w2   (2048x256 @ 256x128)
// 8 rows staged in LDS per block; each thread computes 4 rows for one f,
// amortizing the w2 loads 4x. LDS A-reads are wave-broadcast (free).
// ---------------------------------------------------------------------------
__global__ __launch_bounds__(256) void kern2(
    const float* __restrict__ h1r,       // (2048,256)
    const float* __restrict__ h_w2,      // (256,128)
    float* __restrict__ hs)              // (2048,128)
{
    __shared__ float A[8 * H_];          // 8 KB
    const int t  = threadIdx.x;
    const int r0 = blockIdx.x * 8;

    #pragma unroll
    for (int i = 0; i < 2; ++i) {
        const int flat = t * 4 + i * 1024;
        *(float4*)&A[flat] = *(const float4*)(h1r + (size_t)r0 * H_ + flat);
    }
    __syncthreads();

    const int f  = t & 127;
    const int rg = t >> 7;               // rows rg*4 .. rg*4+3
    const float* Ar  = &A[rg * 4 * H_];
    const float* w2p = h_w2 + f;

    float o0 = 0.f, o1 = 0.f, o2 = 0.f, o3 = 0.f;
    #pragma unroll 2
    for (int k = 0; k < H_; k += 4) {
        const float w0  = w2p[(size_t)(k + 0) * DX_];
        const float w1  = w2p[(size_t)(k + 1) * DX_];
        const float w2v = w2p[(size_t)(k + 2) * DX_];
        const float w3  = w2p[(size_t)(k + 3) * DX_];
        const float4 a0 = *(const float4*)&Ar[0 * H_ + k];
        const float4 a1 = *(const float4*)&Ar[1 * H_ + k];
        const float4 a2 = *(const float4*)&Ar[2 * H_ + k];
        const float4 a3 = *(const float4*)&Ar[3 * H_ + k];
        o0 = fmaf(a0.x, w0, o0); o0 = fmaf(a0.y, w1, o0);
        o0 = fmaf(a0.z, w2v, o0); o0 = fmaf(a0.w, w3, o0);
        o1 = fmaf(a1.x, w0, o1); o1 = fmaf(a1.y, w1, o1);
        o1 = fmaf(a1.z, w2v, o1); o1 = fmaf(a1.w, w3, o1);
        o2 = fmaf(a2.x, w0, o2); o2 = fmaf(a2.y, w1, o2);
        o2 = fmaf(a2.z, w2v, o2); o2 = fmaf(a2.w, w3, o2);
        o3 = fmaf(a3.x, w0, o3); o3 = fmaf(a3.y, w1, o3);
        o3 = fmaf(a3.z, w2v, o3); o3 = fmaf(a3.w, w3, o3);
    }
    float* dst = hs + ((size_t)r0 + rg * 4) * DX_ + f;
    dst[0 * DX_] = o0;
    dst[1 * DX_] = o1;
    dst[2 * DX_] = o2;
    dst[3 * DX_] = o3;
}

// ---------------------------------------------------------------------------
// kern3 (grid 1152 = one block per (b,k), 256 threads): logits+softmax+agg.
// No big LDS stage (pre_s[b] is L2-hot, shared by 36 blocks). Lane = h-quad
// (float4, coalesced); wave handles 16 m's with 6-step shfl_xor reduce;
// softmax in wave 0; agg reads precomputed hs (h_b2 added once, sum att = 1).
// ---------------------------------------------------------------------------
__global__ __launch_bounds__(256) void kern3(
    const float* __restrict__ pre_s,     // (2048,256)
    const float* __restrict__ px,        // (1152,256)
    const float* __restrict__ qpre,      // (32,256)
    const float* __restrict__ score_w2,  // (256,1)
    const float* __restrict__ hs,        // (2048,128)
    const float* __restrict__ h_b2,      // (128)
    const float* __restrict__ x0,        // (1152,128)
    float* __restrict__ out)             // (1152,256)
{
    __shared__ float logit[M_];
    __shared__ float att[M_];
    __shared__ float pr[DX_];

    const int t    = threadIdx.x;
    const int bk   = blockIdx.x;
    const int b    = bk / K_;
    const int lane = t & 63, wave = t >> 6;
    const int hq   = lane << 2;          // h-quad base: 4 h's per lane

    // per-lane constants
    float4 c4, v4;
    {
        const float4 qv = *(const float4*)(qpre + (size_t)b * H_ + hq);
        const float4 pv = *(const float4*)(px + (size_t)bk * H_ + hq);
        c4.x = qv.x + pv.x; c4.y = qv.y + pv.y;
        c4.z = qv.z + pv.z; c4.w = qv.w + pv.w;
        v4 = *(const float4*)(score_w2 + hq);
    }

    // ---- logits: wave handles m = wave*16 .. +15 ----
    const float* ps = pre_s + (size_t)b * M_ * H_;
    #pragma unroll 2
    for (int mi = 0; mi < 16; ++mi) {
        const int m = wave * 16 + mi;
        const float4 p = *(const float4*)(ps + (size_t)m * H_ + hq);
        float x = fmaxf(p.x + c4.x, 0.f) * v4.x
                + fmaxf(p.y + c4.y, 0.f) * v4.y
                + fmaxf(p.z + c4.z, 0.f) * v4.z
                + fmaxf(p.w + c4.w, 0.f) * v4.w;
        #pragma unroll
        for (int off = 32; off > 0; off >>= 1)
            x += __shfl_xor(x, off, 64);
        if (lane == 0) logit[m] = x;
    }
    __syncthreads();

    // ---- softmax over m (wave 0, lane = m) ----
    if (wave == 0) {
        const float L = logit[lane];
        float mx = L;
        #pragma unroll
        for (int off = 32; off > 0; off >>= 1)
            mx = fmaxf(mx, __shfl_xor(mx, off, 64));
        const float e = expf(L - mx);
        float sm = e;
        #pragma unroll
        for (int off = 32; off > 0; off >>= 1)
            sm += __shfl_xor(sm, off, 64);
        att[lane] = e / sm;
    }
    __syncthreads();

    // ---- agg: out[bk,128+f] = sum_m att[m]*hs[b,m,f] + h_b2[f] ----
    const int f = t & 127, mh = t >> 7;
    {
        const float* hsp = hs + ((size_t)b * M_ + mh * 32) * DX_ + f;
        float r = 0.f;
        #pragma unroll 4
        for (int m2 = 0; m2 < 32; ++m2)
            r = fmaf(att[mh * 32 + m2], hsp[(size_t)m2 * DX_], r);
        if (mh) pr[f] = r;
        __syncthreads();
        if (!mh)
            out[(size_t)bk * (2 * DX_) + DX_ + f] = r + pr[f] + h_b2[f];
    }
    // ---- passthrough out[:,0:128] = x0 ----
    if (t < DX_)
        out[(size_t)bk * (2 * DX_) + t] = x0[(size_t)bk * DX_ + t];
}

extern "C" void kernel_launch(void* const* d_in, const int* in_sizes, int n_in,
                              void* d_out, int out_size, void* d_ws, size_t ws_size,
                              hipStream_t stream) {
    (void)in_sizes; (void)n_in; (void)out_size; (void)ws_size;
    const float* s2       = (const float*)d_in[0];
    const float* x0       = (const float*)d_in[1];
    const float* q        = (const float*)d_in[2];
    const float* score_w1 = (const float*)d_in[3];
    const float* score_b1 = (const float*)d_in[4];
    const float* score_w2 = (const float*)d_in[5];
    // d_in[6] = score_b2 (cancels in softmax)
    const float* h_w1     = (const float*)d_in[7];
    const float* h_b1     = (const float*)d_in[8];
    const float* h_w2     = (const float*)d_in[9];
    const float* h_b2     = (const float*)d_in[10];
    float* out = (float*)d_out;

    float* ws    = (float*)d_ws;
    float* pre_s = ws;                                   // 2048*256
    float* h1r   = pre_s + (size_t)B_ * M_ * H_;         // 2048*256
    float* px    = h1r   + (size_t)B_ * M_ * H_;         // 1152*256
    float* qpre  = px    + (size_t)B_ * K_ * H_;         // 32*256
    float* hs    = qpre  + (size_t)B_ * H_;              // 2048*128

    kern1<<<S2B + PXB + QPB, 512, 0, stream>>>(
        s2, x0, q, score_w1, score_b1, h_w1, h_b1, pre_s, h1r, px, qpre);
    kern2<<<256, 256, 0, stream>>>(h1r, h_w2, hs);
    kern3<<<B_ * K_, 256, 0, stream>>>(pre_s, px, qpre, score_w2, hs, h_b2,
                                       x0, out);
}